// Round 1
// baseline (3785.966 us; speedup 1.0000x reference)
//
#include <hip/hip_runtime.h>
#include <hip/hip_bf16.h>
#include <cstdint>

#define NNODES 50000
#define NEDGES 800000
#define DIN 128
#define HID 256
#define NCLS 40
#define NBLK 3
#define EPSV 1e-5f

// ---------------- CSR build ----------------
__global__ void hist_kernel(const int* __restrict__ dst, int* __restrict__ cnt, int E) {
  int e = blockIdx.x * blockDim.x + threadIdx.x;
  if (e < E) atomicAdd(&cnt[dst[e]], 1);
}

__global__ void scan_kernel(const int* __restrict__ cnt, int* __restrict__ row_ptr,
                            float* __restrict__ inv_cnt, int N) {
  __shared__ int sums[1024];
  int t = threadIdx.x;
  int chunk = (N + 1023) >> 10;
  int beg = t * chunk;
  int end = beg + chunk; if (end > N) end = N;
  int s = 0;
  for (int i = beg; i < end; ++i) s += cnt[i];
  sums[t] = s;
  __syncthreads();
  for (int off = 1; off < 1024; off <<= 1) {
    int v = 0;
    if (t >= off) v = sums[t - off];
    __syncthreads();
    sums[t] += v;
    __syncthreads();
  }
  int run = (t == 0) ? 0 : sums[t - 1];
  for (int i = beg; i < end; ++i) {
    row_ptr[i] = run;
    int c = cnt[i];
    inv_cnt[i] = 1.0f / (float)(c > 0 ? c : 1);
    run += c;
  }
  if (t == 1023) row_ptr[N] = run;
}

__global__ void fill_kernel(const int* __restrict__ src, const int* __restrict__ dst,
                            const int* __restrict__ row_ptr, int* __restrict__ fillc,
                            int* __restrict__ col, int E) {
  int e = blockIdx.x * blockDim.x + threadIdx.x;
  if (e < E) {
    int d = dst[e];
    int pos = atomicAdd(&fillc[d], 1);
    col[row_ptr[d] + pos] = src[e];
  }
}

// ---------------- mean aggregation: one block per node ----------------
__global__ __launch_bounds__(256)
void agg_kernel(const float* __restrict__ x, float* __restrict__ out,
                const int* __restrict__ row_ptr, const int* __restrict__ col,
                const float* __restrict__ inv_cnt) {
  int n = blockIdx.x;
  int h = threadIdx.x;
  int beg = row_ptr[n], end = row_ptr[n + 1];
  float s = 0.0f;
  for (int j = beg; j < end; ++j) {
    int c = col[j];
    s += x[(long)c * HID + h];
  }
  out[(long)n * HID + h] = s * inv_cnt[n];
}

// ---------------- fold BN params: S = g*rsqrt(v+eps), T = (bl-m)*S + b ----------------
__global__ void fold_kernel(const float* __restrict__ b1l, const float* __restrict__ g1,
                            const float* __restrict__ bb1, const float* __restrict__ m1,
                            const float* __restrict__ v1,
                            const float* __restrict__ b2l, const float* __restrict__ g2,
                            const float* __restrict__ bb2, const float* __restrict__ m2,
                            const float* __restrict__ v2,
                            float* __restrict__ S1, float* __restrict__ T1,
                            float* __restrict__ S2, float* __restrict__ T2) {
  int idx = blockIdx.x * 256 + threadIdx.x;  // 0..767
  float s1 = g1[idx] * rsqrtf(v1[idx] + EPSV);
  S1[idx] = s1;
  T1[idx] = (b1l[idx] - m1[idx]) * s1 + bb1[idx];
  float s2 = g2[idx] * rsqrtf(v2[idx] + EPSV);
  S2[idx] = s2;
  T2[idx] = (b2l[idx] - m2[idx]) * s2 + bb2[idx];
}

// ---------------- fused fp32 GEMM ----------------
// C[M,BN] = epi( A1[M,K1]@W1[K1,BN] (+ A2@W2) ), epi: *S+T, relu, resid, gate
// BN == full output width (so in-place C == A1 is safe: a block only reads its own rows).
template<int BN, bool GATED>
__global__ __launch_bounds__(256)
void gemm_fused(const float* __restrict__ A1, const float* __restrict__ W1, int K1,
                const float* __restrict__ A2, const float* __restrict__ W2, int K2,
                const float* __restrict__ GW, const float* __restrict__ Gb,
                const float* __restrict__ Sc, const float* __restrict__ Tc,
                const float* __restrict__ resid, float* __restrict__ C,
                int M, int do_relu) {
  constexpr int BM = 64;
  constexpr int BK = 16;
  constexpr int TXN = BN / 8;    // threads along n (each covers 8 cols, split 4+4)
  constexpr int TYN = 256 / TXN; // threads along m
  constexpr int TM = BM / TYN;   // rows per thread
  __shared__ float As[BK][BM];
  __shared__ float Bs[BK][BN + 4];
  const int tid = threadIdx.x;
  const int tx = tid % TXN;
  const int ty = tid / TXN;
  const int m0 = blockIdx.x * BM;

  float acc1[TM][8];
#pragma unroll
  for (int i = 0; i < TM; i++)
#pragma unroll
    for (int j = 0; j < 8; j++) acc1[i][j] = 0.0f;
  float acc2[GATED ? TM : 1][GATED ? 8 : 1];
  if constexpr (GATED) {
#pragma unroll
    for (int i = 0; i < TM; i++)
#pragma unroll
      for (int j = 0; j < 8; j++) acc2[i][j] = 0.0f;
  }

  auto phase = [&](const float* __restrict__ A, const float* __restrict__ W, int K, auto& acc) {
    const int lm = tid >> 2;        // 0..63 : A row within tile
    const int lk = (tid & 3) * 4;   // 0,4,8,12
    const int wk = tid >> 4;        // 0..15 : W row within tile
    const int wn0 = (tid & 15) * (BN / 16);
    for (int kt = 0; kt < K; kt += BK) {
      float4 av = make_float4(0.f, 0.f, 0.f, 0.f);
      int arow = m0 + lm;
      if (arow < M) av = *reinterpret_cast<const float4*>(A + (long)arow * K + kt + lk);
      float4 wv[BN / 64];
#pragma unroll
      for (int q = 0; q < BN / 64; q++)
        wv[q] = *reinterpret_cast<const float4*>(W + (long)(kt + wk) * BN + wn0 + q * 4);
      __syncthreads();  // previous tile fully consumed before overwrite
      As[lk + 0][lm] = av.x; As[lk + 1][lm] = av.y;
      As[lk + 2][lm] = av.z; As[lk + 3][lm] = av.w;
#pragma unroll
      for (int q = 0; q < BN / 64; q++)
        *reinterpret_cast<float4*>(&Bs[wk][wn0 + q * 4]) = wv[q];
      __syncthreads();
#pragma unroll
      for (int k = 0; k < BK; k++) {
        float a[TM];
#pragma unroll
        for (int ii = 0; ii < TM; ii += 4) {
          float4 a4 = *reinterpret_cast<const float4*>(&As[k][ty * TM + ii]);
          a[ii] = a4.x; a[ii + 1] = a4.y; a[ii + 2] = a4.z; a[ii + 3] = a4.w;
        }
        float b[8];
        float4 b0 = *reinterpret_cast<const float4*>(&Bs[k][tx * 4]);
        float4 b1 = *reinterpret_cast<const float4*>(&Bs[k][BN / 2 + tx * 4]);
        b[0] = b0.x; b[1] = b0.y; b[2] = b0.z; b[3] = b0.w;
        b[4] = b1.x; b[5] = b1.y; b[6] = b1.z; b[7] = b1.w;
#pragma unroll
        for (int i = 0; i < TM; i++)
#pragma unroll
          for (int j = 0; j < 8; j++)
            acc[i][j] = fmaf(a[i], b[j], acc[i][j]);
      }
    }
  };

  phase(A1, W1, K1, acc1);
  if (A2) phase(A2, W2, K2, acc1);
  if constexpr (GATED) phase(resid, GW, HID, acc2);

#pragma unroll
  for (int i = 0; i < TM; i++) {
    int row = m0 + ty * TM + i;
    if (row < M) {
#pragma unroll
      for (int j = 0; j < 8; j++) {
        int cn = (j < 4) ? (tx * 4 + j) : (BN / 2 + tx * 4 + (j - 4));
        float v = acc1[i][j];
        float sc = Sc ? Sc[cn] : 1.0f;
        v = v * sc + Tc[cn];
        if (do_relu) v = fmaxf(v, 0.0f);
        if constexpr (GATED) {
          float p = resid[(long)row * BN + cn];
          float g = 1.0f / (1.0f + __expf(-(acc2[i][j] + Gb[cn])));
          v = g * p + (1.0f - g) * (v + p);
        } else if (resid) {
          v += resid[(long)row * BN + cn];
        }
        C[(long)row * BN + cn] = v;
      }
    }
  }
}

// ---------------- classifier stage 2: [M,128] @ [128,40] + b ----------------
__global__ __launch_bounds__(256)
void classifier2(const float* __restrict__ Tin, const float* __restrict__ W,
                 const float* __restrict__ bias, float* __restrict__ out, int M) {
  __shared__ float Ws[DIN * NCLS];
  __shared__ float bs[NCLS];
  __shared__ float Ts[64][DIN + 4];
  int tid = threadIdx.x;
  for (int i = tid; i < DIN * NCLS; i += 256) Ws[i] = W[i];
  if (tid < NCLS) bs[tid] = bias[tid];
  int row0 = blockIdx.x * 64;
  for (int idx = tid; idx < 64 * (DIN / 4); idx += 256) {
    int r = idx / (DIN / 4);
    int c4 = idx % (DIN / 4);
    float4 v = make_float4(0.f, 0.f, 0.f, 0.f);
    if (row0 + r < M) v = *reinterpret_cast<const float4*>(Tin + (long)(row0 + r) * DIN + c4 * 4);
    *reinterpret_cast<float4*>(&Ts[r][c4 * 4]) = v;
  }
  __syncthreads();
  int r = tid >> 2;
  int c0 = (tid & 3) * 10;
  float s[10];
#pragma unroll
  for (int c = 0; c < 10; c++) s[c] = bs[c0 + c];
  for (int k = 0; k < DIN; k++) {
    float a = Ts[r][k];
#pragma unroll
    for (int c = 0; c < 10; c++) s[c] = fmaf(a, Ws[k * NCLS + c0 + c], s[c]);
  }
  if (row0 + r < M) {
#pragma unroll
    for (int c = 0; c < 10; c++) out[(long)(row0 + r) * NCLS + c0 + c] = s[c];
  }
}

extern "C" void kernel_launch(void* const* d_in, const int* in_sizes, int n_in,
                              void* d_out, int out_size, void* d_ws, size_t ws_size,
                              hipStream_t stream) {
  const float* x      = (const float*)d_in[0];
  const int*   ei     = (const int*)d_in[1];
  const float* Wp     = (const float*)d_in[2];
  const float* bp     = (const float*)d_in[3];
  const float* W1l    = (const float*)d_in[4];
  const float* b1l    = (const float*)d_in[5];
  const float* W1r    = (const float*)d_in[6];
  const float* W2l    = (const float*)d_in[7];
  const float* b2l    = (const float*)d_in[8];
  const float* W2r    = (const float*)d_in[9];
  const float* bn1_g  = (const float*)d_in[10];
  const float* bn1_b  = (const float*)d_in[11];
  const float* bn1_m  = (const float*)d_in[12];
  const float* bn1_v  = (const float*)d_in[13];
  const float* bn2_g  = (const float*)d_in[14];
  const float* bn2_b  = (const float*)d_in[15];
  const float* bn2_m  = (const float*)d_in[16];
  const float* bn2_v  = (const float*)d_in[17];
  const float* gate_W = (const float*)d_in[18];
  const float* gate_b = (const float*)d_in[19];
  const float* Wc1    = (const float*)d_in[20];
  const float* bc1    = (const float*)d_in[21];
  const float* Wc2    = (const float*)d_in[22];
  const float* bc2    = (const float*)d_in[23];
  const int* srcp = ei;
  const int* dstp = ei + NEDGES;

  char* wsb = (char*)d_ws;
  size_t off = 0;
  auto alloc = [&](size_t bytes) -> void* {
    void* p = wsb + off;
    off += (bytes + 255) & ~(size_t)255;
    return p;
  };
  float* X0 = (float*)alloc((size_t)NNODES * HID * 4);
  float* X1 = (float*)alloc((size_t)NNODES * HID * 4);
  float* X2 = (float*)alloc((size_t)NNODES * HID * 4);
  int* cnt     = (int*)alloc((size_t)NNODES * 4 * 2);  // cnt + fill, contiguous
  int* fillc   = cnt + NNODES;
  int* row_ptr = (int*)alloc((size_t)(NNODES + 1) * 4);
  float* inv   = (float*)alloc((size_t)NNODES * 4);
  int* col     = (int*)alloc((size_t)NEDGES * 4);
  float* S1 = (float*)alloc(NBLK * HID * 4);
  float* T1 = (float*)alloc(NBLK * HID * 4);
  float* S2 = (float*)alloc(NBLK * HID * 4);
  float* T2 = (float*)alloc(NBLK * HID * 4);

  hipMemsetAsync(cnt, 0, (size_t)NNODES * 4 * 2, stream);
  int eb = (NEDGES + 255) / 256;
  hist_kernel<<<eb, 256, 0, stream>>>(dstp, cnt, NEDGES);
  scan_kernel<<<1, 1024, 0, stream>>>(cnt, row_ptr, inv, NNODES);
  fill_kernel<<<eb, 256, 0, stream>>>(srcp, dstp, row_ptr, fillc, col, NEDGES);
  fold_kernel<<<3, 256, 0, stream>>>(b1l, bn1_g, bn1_b, bn1_m, bn1_v,
                                     b2l, bn2_g, bn2_b, bn2_m, bn2_v, S1, T1, S2, T2);

  int gm = (NNODES + 63) / 64;  // 782
  // input projection: X0 = x @ Wp + bp
  gemm_fused<256, false><<<gm, 256, 0, stream>>>(
      x, Wp, DIN, nullptr, nullptr, 0, nullptr, nullptr,
      nullptr, bp, nullptr, X0, NNODES, 0);

  float* bufs[3] = {X0, X1, X2};
  int prev = 0;
  for (int i = 0; i < NBLK; ++i) {
    int bm = (prev + 1) % 3;  // mean, then cur (in-place)
    int bh = (prev + 2) % 3;  // h1
    float* P  = bufs[prev];
    float* Mb = bufs[bm];
    float* Hb = bufs[bh];
    // mean of prev
    agg_kernel<<<NNODES, 256, 0, stream>>>(P, Mb, row_ptr, col, inv);
    // h1 = relu(bn1(mean@W1l + prev@W1r + b1l))
    gemm_fused<256, false><<<gm, 256, 0, stream>>>(
        Mb, W1l + (size_t)i * HID * HID, HID,
        P, W1r + (size_t)i * HID * HID, HID,
        nullptr, nullptr, S1 + i * HID, T1 + i * HID, nullptr, Hb, NNODES, 1);
    // mean of h1 (overwrites Mb)
    agg_kernel<<<NNODES, 256, 0, stream>>>(Hb, Mb, row_ptr, col, inv);
    // cur = [gate] relu(bn2(mean2@W2l + h1@W2r + b2l)) + prev   (in-place into Mb)
    if (i == 0) {
      gemm_fused<256, false><<<gm, 256, 0, stream>>>(
          Mb, W2l, HID, Hb, W2r, HID, nullptr, nullptr,
          S2, T2, P, Mb, NNODES, 1);
    } else {
      gemm_fused<256, true><<<gm, 256, 0, stream>>>(
          Mb, W2l + (size_t)i * HID * HID, HID,
          Hb, W2r + (size_t)i * HID * HID, HID,
          gate_W + (size_t)(i - 1) * HID * HID, gate_b + (size_t)(i - 1) * HID,
          S2 + i * HID, T2 + i * HID, P, Mb, NNODES, 1);
    }
    prev = bm;
  }
  // classifier
  float* P  = bufs[prev];
  float* Tb = bufs[(prev + 1) % 3];
  gemm_fused<128, false><<<gm, 256, 0, stream>>>(
      P, Wc1, HID, nullptr, nullptr, 0, nullptr, nullptr,
      nullptr, bc1, nullptr, Tb, NNODES, 1);
  classifier2<<<gm, 256, 0, stream>>>(Tb, Wc2, bc2, (float*)d_out, NNODES);
}